// Round 12
// baseline (5549.785 us; speedup 1.0000x reference)
//
#include <hip/hip_runtime.h>
#include <cstdint>
#include <cstddef>

#define HH 512
#define BB 64
#define TT 256
#define GG 2048   // 4*HH
#define NCLS 50257
#define NWG 128   // scan grid size (16 wgs per group x 8 groups)

#define PERM_HI 0x05040100u
#define PERM_LO 0x07060302u

typedef __attribute__((ext_vector_type(4))) float f32x4;
typedef __attribute__((ext_vector_type(8))) short bf16x8;
typedef __attribute__((ext_vector_type(4))) unsigned int u32x4;
typedef __attribute__((ext_vector_type(8))) unsigned int u32x8;

__device__ __forceinline__ unsigned short bf16_rn(float x){
    unsigned u = __float_as_uint(x);
    unsigned r = u + 0x7fffu + ((u >> 16) & 1u);
    return (unsigned short)(r >> 16);
}
__device__ __forceinline__ void split2(float x, unsigned short& hi, unsigned short& lo){
    unsigned short h = bf16_rn(x);
    float hf = __uint_as_float(((unsigned)h) << 16);
    lo = bf16_rn(x - hf);
    hi = h;
}
__device__ __forceinline__ bf16x8 mk8(unsigned a, unsigned b, unsigned c, unsigned d){
    u32x4 t; t[0]=a; t[1]=b; t[2]=c; t[3]=d;
    return __builtin_bit_cast(bf16x8, t);
}

// split fp32 -> (bf16 hi, bf16 lo) arrays
__global__ __launch_bounds__(256) void split_bf16_k(
    const float* __restrict__ in, unsigned short* __restrict__ hi,
    unsigned short* __restrict__ lo, int n)
{
    int i = blockIdx.x * 256 + threadIdx.x;
    if (i < n){ unsigned short h, l; split2(in[i], h, l); hi[i] = h; lo[i] = l; }
}

// ---------------- input-projection GEMM via split-bf16 MFMA ----------------------
// out[(t*BB+b)][n] = A[r=b*TT+t][:] . Bw[n][:] + bias1[n]+bias2[n]
// A: layer0 = fp32 emb + gather (split in staging); layer1 = packed u32 (lo16|hi16).
// B: pre-split bf16 hi/lo [2048][512]. Tiles 128x128, BK=32, 4 waves (2x2 of 64x64),
// verified MFMA mapping (same as scan): A row=c16, k=kg*8+j; D row=kg*4+i, col=c16.
__global__ __launch_bounds__(256,2) void gemm_xg_mfma(
    const float* __restrict__ Af32, const unsigned* __restrict__ Apk,
    const int* __restrict__ gather,
    const unsigned short* __restrict__ Bhi, const unsigned short* __restrict__ Blo,
    const float* __restrict__ bias1, const float* __restrict__ bias2,
    float* __restrict__ out)
{
    __shared__ unsigned short Ah[128][40], Al[128][40], Bh[128][40], Bl[128][40];
    const int tid  = threadIdx.x;
    const int lane = tid & 63, wid = tid >> 6;
    const int c16  = lane & 15, kg = lane >> 4;
    const int row0 = blockIdx.y * 128, col0 = blockIdx.x * 128;
    const int wm = (wid >> 1) * 64, wn = (wid & 1) * 64;
    const int sr = tid & 127;          // staged row
    const bool isA = tid < 128;

    f32x4 acc[4][4];
    #pragma unroll
    for (int mi=0;mi<4;mi++)
        #pragma unroll
        for (int ni=0;ni<4;ni++){ acc[mi][ni][0]=0.f; acc[mi][ni][1]=0.f; acc[mi][ni][2]=0.f; acc[mi][ni][3]=0.f; }

    for (int ks = 0; ks < 16; ks++){
        const int k0 = ks * 32;
        if (isA){
            if (Apk){       // layer 1: packed bf16 pairs
                const unsigned* src = Apk + (size_t)(row0 + sr) * HH + k0;
                u32x4 v[8];
                #pragma unroll
                for (int q=0;q<8;q++) v[q] = *(const u32x4*)(src + q*4);
                #pragma unroll
                for (int g=0; g<4; g++){
                    u32x4 h4, l4;
                    h4[0]=__builtin_amdgcn_perm(v[2*g][1],   v[2*g][0],   PERM_HI);
                    h4[1]=__builtin_amdgcn_perm(v[2*g][3],   v[2*g][2],   PERM_HI);
                    h4[2]=__builtin_amdgcn_perm(v[2*g+1][1], v[2*g+1][0], PERM_HI);
                    h4[3]=__builtin_amdgcn_perm(v[2*g+1][3], v[2*g+1][2], PERM_HI);
                    l4[0]=__builtin_amdgcn_perm(v[2*g][1],   v[2*g][0],   PERM_LO);
                    l4[1]=__builtin_amdgcn_perm(v[2*g][3],   v[2*g][2],   PERM_LO);
                    l4[2]=__builtin_amdgcn_perm(v[2*g+1][1], v[2*g+1][0], PERM_LO);
                    l4[3]=__builtin_amdgcn_perm(v[2*g+1][3], v[2*g+1][2], PERM_LO);
                    *(u32x4*)&Ah[sr][g*8] = h4;
                    *(u32x4*)&Al[sr][g*8] = l4;
                }
            } else {        // layer 0: fp32 gather + split
                const float* src = Af32 + (size_t)gather[row0 + sr] * HH + k0;
                float f[32];
                #pragma unroll
                for (int q=0;q<8;q++) *(float4*)&f[q*4] = *(const float4*)(src + q*4);
                #pragma unroll
                for (int g=0; g<4; g++){
                    unsigned short h[8], l[8];
                    #pragma unroll
                    for (int j=0;j<8;j++) split2(f[g*8+j], h[j], l[j]);
                    u32x4 h4, l4;
                    #pragma unroll
                    for (int q=0;q<4;q++){
                        h4[q] = (((unsigned)h[2*q+1])<<16) | (unsigned)h[2*q];
                        l4[q] = (((unsigned)l[2*q+1])<<16) | (unsigned)l[2*q];
                    }
                    *(u32x4*)&Ah[sr][g*8] = h4;
                    *(u32x4*)&Al[sr][g*8] = l4;
                }
            }
        } else {            // B rows (pre-split)
            const unsigned short* sh = Bhi + (size_t)(col0 + sr) * HH + k0;
            const unsigned short* sl = Blo + (size_t)(col0 + sr) * HH + k0;
            #pragma unroll
            for (int g=0; g<4; g++){
                *(u32x4*)&Bh[sr][g*8] = *(const u32x4*)(sh + g*8);
                *(u32x4*)&Bl[sr][g*8] = *(const u32x4*)(sl + g*8);
            }
        }
        __syncthreads();

        bf16x8 ah[4], al[4];
        #pragma unroll
        for (int mi=0;mi<4;mi++){
            ah[mi] = *(const bf16x8*)&Ah[wm + mi*16 + c16][kg*8];
            al[mi] = *(const bf16x8*)&Al[wm + mi*16 + c16][kg*8];
        }
        #pragma unroll
        for (int ni=0;ni<4;ni++){
            bf16x8 bh = *(const bf16x8*)&Bh[wn + ni*16 + c16][kg*8];
            bf16x8 bl = *(const bf16x8*)&Bl[wn + ni*16 + c16][kg*8];
            #pragma unroll
            for (int mi=0;mi<4;mi++){
                acc[mi][ni] = __builtin_amdgcn_mfma_f32_16x16x32_bf16(ah[mi], bh, acc[mi][ni], 0,0,0);
                acc[mi][ni] = __builtin_amdgcn_mfma_f32_16x16x32_bf16(ah[mi], bl, acc[mi][ni], 0,0,0);
                acc[mi][ni] = __builtin_amdgcn_mfma_f32_16x16x32_bf16(al[mi], bh, acc[mi][ni], 0,0,0);
            }
        }
        __syncthreads();
    }
    // epilogue
    float bs[4];
    #pragma unroll
    for (int ni=0;ni<4;ni++){
        int c = col0 + wn + ni*16 + c16;
        bs[ni] = bias1[c] + bias2[c];
    }
    #pragma unroll
    for (int mi=0;mi<4;mi++){
        #pragma unroll
        for (int i=0;i<4;i++){
            int R = row0 + wm + mi*16 + kg*4 + i;
            int b = R >> 8, t = R & 255;
            float* op = out + (size_t)(t*BB + b)*GG + col0 + wn;
            #pragma unroll
            for (int ni=0;ni<4;ni++)
                op[ni*16 + c16] = acc[mi][ni][i] + bs[ni];
        }
    }
}

// ---------------- persistent LSTM scan (split-bf16 MFMA, epoch barrier) ----------
// Weights staged in LDS (immune to the per-step L2 invalidate). Two accumulators
// break the 48-deep dependent MFMA chain. Barrier unchanged (round-9-validated).
__global__ __launch_bounds__(256,1) void lstm_scan_mfma(
    const float* __restrict__ xg,            // [TT][BB][GG]
    const unsigned short* __restrict__ Whi,  // [GG][HH] bf16-hi
    const unsigned short* __restrict__ Wlo,  // [GG][HH] bf16-lo
    unsigned* __restrict__ hpk,              // [2][BB][HH] packed (lo<<16)|hi
    unsigned* __restrict__ hseq_pk,          // mode1: [BB*TT][HH] packed
    float* __restrict__ hlast,               // mode0: [BB][HH] fp32
    int* __restrict__ bar,                   // zeroed: [0]=epoch, 32+g*32 groups, 288 root
    int mode)
{
    __shared__ unsigned short Wh[8192];      // [kt][kg][16 rows][8]  (16 KB)
    __shared__ unsigned short Wl[8192];
    __shared__ float gs[BB][17];
    const int tid  = threadIdx.x;
    const int lane = tid & 63, wv = tid >> 6;
    const int wg   = blockIdx.x;
    const int j0   = wg * 4;
    const int c16  = lane & 15, kg = lane >> 4;

    // stage weight slice to LDS: thread = (row rr, k-tile kseg)
    {
        const int rr = tid >> 4, kseg = tid & 15;
        const int grow = (rr >> 2) * HH + j0 + (rr & 3);
        const unsigned short* ph = Whi + (size_t)grow * HH + kseg * 32;
        const unsigned short* pl = Wlo + (size_t)grow * HH + kseg * 32;
        #pragma unroll
        for (int g=0; g<4; g++){
            *(u32x4*)&Wh[((kseg*4 + g)*16 + rr)*8] = *(const u32x4*)(ph + g*8);
            *(u32x4*)&Wl[((kseg*4 + g)*16 + rr)*8] = *(const u32x4*)(pl + g*8);
        }
    }
    __syncthreads();

    const int arow = wv * 16 + c16;                    // A row (batch) this lane loads
    const int xcol = (c16 >> 2) * HH + j0 + (c16 & 3); // xg gate column
    const int b0   = wv * 16 + kg * 4;                 // D rows base (4 batches)
    const int ab   = tid >> 2, ad = tid & 3;           // activation: (batch, dim)

    float c_st = 0.f;

    // prime xg accumulator for t=0
    f32x4 cur;
    {
        const float* xp = xg + xcol;
        cur[0] = xp[(size_t)(b0 + 0) * GG];
        cur[1] = xp[(size_t)(b0 + 1) * GG];
        cur[2] = xp[(size_t)(b0 + 2) * GG];
        cur[3] = xp[(size_t)(b0 + 3) * GG];
    }

    for (int t = 0; t < TT; t++){
        const unsigned* hin  = hpk + (size_t)(t & 1) * BB * HH;
        unsigned*       hout = hpk + (size_t)((t + 1) & 1) * BB * HH;

        f32x4 acc0 = cur;
        f32x4 acc1; acc1[0]=0.f; acc1[1]=0.f; acc1[2]=0.f; acc1[3]=0.f;
        const unsigned* pa = hin + (size_t)arow * HH + kg * 8;
        #pragma unroll
        for (int kt = 0; kt < 16; kt++){
            u32x8 w = *(const u32x8*)(pa + kt * 32);
            unsigned h01 = __builtin_amdgcn_perm(w[1], w[0], PERM_HI);
            unsigned h23 = __builtin_amdgcn_perm(w[3], w[2], PERM_HI);
            unsigned h45 = __builtin_amdgcn_perm(w[5], w[4], PERM_HI);
            unsigned h67 = __builtin_amdgcn_perm(w[7], w[6], PERM_HI);
            unsigned l01 = __builtin_amdgcn_perm(w[1], w[0], PERM_LO);
            unsigned l23 = __builtin_amdgcn_perm(w[3], w[2], PERM_LO);
            unsigned l45 = __builtin_amdgcn_perm(w[5], w[4], PERM_LO);
            unsigned l67 = __builtin_amdgcn_perm(w[7], w[6], PERM_LO);
            bf16x8 a_h = mk8(h01, h23, h45, h67);
            bf16x8 a_l = mk8(l01, l23, l45, l67);
            bf16x8 wbh = *(const bf16x8*)&Wh[((kt*4 + kg)*16 + c16)*8];
            bf16x8 wbl = *(const bf16x8*)&Wl[((kt*4 + kg)*16 + c16)*8];
            if (kt & 1){
                acc1 = __builtin_amdgcn_mfma_f32_16x16x32_bf16(a_h, wbh, acc1, 0,0,0);
                acc1 = __builtin_amdgcn_mfma_f32_16x16x32_bf16(a_h, wbl, acc1, 0,0,0);
                acc1 = __builtin_amdgcn_mfma_f32_16x16x32_bf16(a_l, wbh, acc1, 0,0,0);
            } else {
                acc0 = __builtin_amdgcn_mfma_f32_16x16x32_bf16(a_h, wbh, acc0, 0,0,0);
                acc0 = __builtin_amdgcn_mfma_f32_16x16x32_bf16(a_h, wbl, acc0, 0,0,0);
                acc0 = __builtin_amdgcn_mfma_f32_16x16x32_bf16(a_l, wbh, acc0, 0,0,0);
            }
        }
        // D -> LDS (lane holds D[b0+r][c16])
        gs[b0 + 0][c16] = acc0[0] + acc1[0];
        gs[b0 + 1][c16] = acc0[1] + acc1[1];
        gs[b0 + 2][c16] = acc0[2] + acc1[2];
        gs[b0 + 3][c16] = acc0[3] + acc1[3];
        __syncthreads();
        {
            float gi = gs[ab][ad], gf = gs[ab][4 + ad], gg = gs[ab][8 + ad], go = gs[ab][12 + ad];
            gi = 1.f / (1.f + expf(-gi));
            gf = 1.f / (1.f + expf(-gf));
            gg = tanhf(gg);
            go = 1.f / (1.f + expf(-go));
            c_st = gf * c_st + gi * gg;
            float h = go * tanhf(c_st);
            unsigned short hb, lb; split2(h, hb, lb);
            unsigned pk = (((unsigned)lb) << 16) | (unsigned)hb;
            __hip_atomic_store(&hout[(size_t)ab * HH + j0 + ad], pk,
                               __ATOMIC_RELAXED, __HIP_MEMORY_SCOPE_AGENT);
            if (mode) hseq_pk[(size_t)(ab * TT + t) * HH + j0 + ad] = pk;
            else      hlast[(size_t)ab * HH + j0 + ad] = h;
        }
        // ---- epoch barrier (round-9-validated) ----
        __syncthreads();
        if (tid == 0){
            const int g = wg & 7;
            int old = __hip_atomic_fetch_add(bar + 32 + g * 32, 1,
                        __ATOMIC_RELAXED, __HIP_MEMORY_SCOPE_AGENT);
            if (old == (NWG / 8) * (t + 1) - 1){
                int r = __hip_atomic_fetch_add(bar + 288, 1,
                            __ATOMIC_RELAXED, __HIP_MEMORY_SCOPE_AGENT);
                if (r == 8 * (t + 1) - 1){
                    __hip_atomic_store(bar, t + 1,
                        __ATOMIC_RELAXED, __HIP_MEMORY_SCOPE_AGENT);
                }
            }
        }
        // prefetch next-step xg into regs (overlaps the spin below)
        {
            const int tp = (t + 1 < TT) ? t + 1 : t;
            const float* xp = xg + (size_t)tp * BB * GG + xcol;
            cur[0] = xp[(size_t)(b0 + 0) * GG];
            cur[1] = xp[(size_t)(b0 + 1) * GG];
            cur[2] = xp[(size_t)(b0 + 2) * GG];
            cur[3] = xp[(size_t)(b0 + 3) * GG];
        }
        if (tid == 0){
            while (__hip_atomic_load(bar, __ATOMIC_RELAXED, __HIP_MEMORY_SCOPE_AGENT) < t + 1)
                __builtin_amdgcn_s_sleep(2);
            __builtin_amdgcn_fence(__ATOMIC_ACQUIRE, "agent");   // inv stale h lines
        }
        __syncthreads();
    }
}

// logits: out[b][v] = sum_k h[b][k]*W[v][k] + bias[v]; M=64, N=50257, K=512
__global__ __launch_bounds__(256) void gemm_logits(
    const float* __restrict__ hlast, const float* __restrict__ W,
    const float* __restrict__ bias, float* __restrict__ out)
{
    __shared__ float As[32][68];
    __shared__ float Bs[32][68];
    const int tid = threadIdx.x;
    const int col0 = blockIdx.x * 64;
    const int tx = tid & 15, ty = tid >> 4;
    float acc[4][4];
    #pragma unroll
    for (int i=0;i<4;i++)
        #pragma unroll
        for (int j=0;j<4;j++) acc[i][j]=0.f;

    for (int k0=0;k0<HH;k0+=32){
        #pragma unroll
        for (int i=0;i<2;i++){
            int f = tid + i*256;
            int r = f>>3, kq = f&7;
            float4 v = *(const float4*)(hlast + (size_t)r*HH + k0 + kq*4);
            As[kq*4+0][r]=v.x; As[kq*4+1][r]=v.y; As[kq*4+2][r]=v.z; As[kq*4+3][r]=v.w;
        }
        #pragma unroll
        for (int i=0;i<2;i++){
            int f = tid + i*256;
            int r = f>>3, kq = f&7;
            int vrow = col0 + r;
            float4 v = make_float4(0.f,0.f,0.f,0.f);
            if (vrow < NCLS) v = *(const float4*)(W + (size_t)vrow*HH + k0 + kq*4);
            Bs[kq*4+0][r]=v.x; Bs[kq*4+1][r]=v.y; Bs[kq*4+2][r]=v.z; Bs[kq*4+3][r]=v.w;
        }
        __syncthreads();
        #pragma unroll
        for (int kk=0;kk<32;kk++){
            float4 a4 = *(float4*)&As[kk][ty*4];
            float4 b4 = *(float4*)&Bs[kk][tx*4];
            float a[4] = {a4.x,a4.y,a4.z,a4.w};
            float b[4] = {b4.x,b4.y,b4.z,b4.w};
            #pragma unroll
            for (int i=0;i<4;i++)
                #pragma unroll
                for (int j=0;j<4;j++) acc[i][j] += a[i]*b[j];
        }
        __syncthreads();
    }
    #pragma unroll
    for (int i=0;i<4;i++){
        int b = ty*4 + i;
        #pragma unroll
        for (int j=0;j<4;j++){
            int v = col0 + tx*4 + j;
            if (v < NCLS) out[(size_t)b*NCLS + v] = acc[i][j] + bias[v];
        }
    }
}

extern "C" void kernel_launch(void* const* d_in, const int* in_sizes, int n_in,
                              void* d_out, int out_size, void* d_ws, size_t ws_size,
                              hipStream_t stream)
{
    const int*   X     = (const int*)  d_in[0];
    const float* emb   = (const float*)d_in[1];
    const float* w_ih0 = (const float*)d_in[2];
    const float* w_hh0 = (const float*)d_in[3];
    const float* b_ih0 = (const float*)d_in[4];
    const float* b_hh0 = (const float*)d_in[5];
    const float* w_ih1 = (const float*)d_in[6];
    const float* w_hh1 = (const float*)d_in[7];
    const float* b_ih1 = (const float*)d_in[8];
    const float* b_hh1 = (const float*)d_in[9];
    const float* Wout  = (const float*)d_in[10];
    const float* bout  = (const float*)d_in[11];
    float* out = (float*)d_out;

    float* ws = (float*)d_ws;
    float*          xg      = ws;                               // 33,554,432 f
    unsigned*       hseq_pk = (unsigned*)(ws + 33554432);       // 8,388,608 u32
    float*          hlast   = ws + 41943040;                    // 32,768 f
    unsigned short* Shi     = (unsigned short*)(ws + 41975808); // 1,048,576 shorts
    unsigned short* Slo     = (unsigned short*)(ws + 42500096);
    unsigned*       hpk     = (unsigned*)(ws + 43024384);       // 65,536 u32
    int*            bar     = (int*)(ws + 43089920);            // 4 KB
    // total 43,090,944 f = 172.4 MB (< proven 176.6 MB footprint)

    dim3 gemmGrid(16, 128);

    // ---- layer 0
    split_bf16_k<<<4096, 256, 0, stream>>>(w_ih0, Shi, Slo, GG*HH);
    gemm_xg_mfma<<<gemmGrid, 256, 0, stream>>>(emb, nullptr, X, Shi, Slo, b_ih0, b_hh0, xg);
    split_bf16_k<<<4096, 256, 0, stream>>>(w_hh0, Shi, Slo, GG*HH);
    hipMemsetAsync(hpk, 0, (size_t)2*BB*HH*sizeof(unsigned), stream);
    hipMemsetAsync(bar, 0, 4096, stream);
    {
        const float* a0 = xg; const unsigned short *a1 = Shi, *a2 = Slo;
        unsigned* a3 = hpk; unsigned* a4 = hseq_pk; float* a5 = hlast; int* a6 = bar; int a7 = 1;
        void* args[] = {&a0,&a1,&a2,&a3,&a4,&a5,&a6,&a7};
        hipLaunchCooperativeKernel((void*)lstm_scan_mfma, dim3(NWG), dim3(256), args, 0, stream);
    }
    // ---- layer 1
    split_bf16_k<<<4096, 256, 0, stream>>>(w_ih1, Shi, Slo, GG*HH);
    gemm_xg_mfma<<<gemmGrid, 256, 0, stream>>>(nullptr, hseq_pk, nullptr, Shi, Slo, b_ih1, b_hh1, xg);
    split_bf16_k<<<4096, 256, 0, stream>>>(w_hh1, Shi, Slo, GG*HH);
    hipMemsetAsync(hpk, 0, (size_t)2*BB*HH*sizeof(unsigned), stream);
    hipMemsetAsync(bar, 0, 4096, stream);
    {
        const float* a0 = xg; const unsigned short *a1 = Shi, *a2 = Slo;
        unsigned* a3 = hpk; unsigned* a4 = hseq_pk; float* a5 = hlast; int* a6 = bar; int a7 = 0;
        void* args[] = {&a0,&a1,&a2,&a3,&a4,&a5,&a6,&a7};
        hipLaunchCooperativeKernel((void*)lstm_scan_mfma, dim3(NWG), dim3(256), args, 0, stream);
    }
    gemm_logits<<<786, 256, 0, stream>>>(hlast, Wout, bout, out);
}

// Round 13
// 4386.450 us; speedup vs baseline: 1.2652x; 1.2652x over previous
//
#include <hip/hip_runtime.h>
#include <cstdint>
#include <cstddef>

#define HH 512
#define BB 64
#define TT 256
#define GG 2048   // 4*HH
#define NCLS 50257
#define NWG 128   // scan grid size (16 wgs per group x 8 groups)

#define PERM_HI 0x05040100u
#define PERM_LO 0x07060302u

typedef __attribute__((ext_vector_type(4))) float f32x4;
typedef __attribute__((ext_vector_type(8))) short bf16x8;
typedef __attribute__((ext_vector_type(4))) unsigned int u32x4;
typedef __attribute__((ext_vector_type(8))) unsigned int u32x8;

__device__ __forceinline__ unsigned short bf16_rn(float x){
    unsigned u = __float_as_uint(x);
    unsigned r = u + 0x7fffu + ((u >> 16) & 1u);
    return (unsigned short)(r >> 16);
}
__device__ __forceinline__ void split2(float x, unsigned short& hi, unsigned short& lo){
    unsigned short h = bf16_rn(x);
    float hf = __uint_as_float(((unsigned)h) << 16);
    lo = bf16_rn(x - hf);
    hi = h;
}
__device__ __forceinline__ bf16x8 mk8(unsigned a, unsigned b, unsigned c, unsigned d){
    u32x4 t; t[0]=a; t[1]=b; t[2]=c; t[3]=d;
    return __builtin_bit_cast(bf16x8, t);
}

// split fp32 -> (bf16 hi, bf16 lo) arrays
__global__ __launch_bounds__(256) void split_bf16_k(
    const float* __restrict__ in, unsigned short* __restrict__ hi,
    unsigned short* __restrict__ lo, int n)
{
    int i = blockIdx.x * 256 + threadIdx.x;
    if (i < n){ unsigned short h, l; split2(in[i], h, l); hi[i] = h; lo[i] = l; }
}

// ---------------- input-projection GEMM via split-bf16 MFMA (r12-validated) ------
__global__ __launch_bounds__(256,2) void gemm_xg_mfma(
    const float* __restrict__ Af32, const unsigned* __restrict__ Apk,
    const int* __restrict__ gather,
    const unsigned short* __restrict__ Bhi, const unsigned short* __restrict__ Blo,
    const float* __restrict__ bias1, const float* __restrict__ bias2,
    float* __restrict__ out)
{
    __shared__ unsigned short Ah[128][40], Al[128][40], Bh[128][40], Bl[128][40];
    const int tid  = threadIdx.x;
    const int lane = tid & 63, wid = tid >> 6;
    const int c16  = lane & 15, kg = lane >> 4;
    const int row0 = blockIdx.y * 128, col0 = blockIdx.x * 128;
    const int wm = (wid >> 1) * 64, wn = (wid & 1) * 64;
    const int sr = tid & 127;          // staged row
    const bool isA = tid < 128;

    f32x4 acc[4][4];
    #pragma unroll
    for (int mi=0;mi<4;mi++)
        #pragma unroll
        for (int ni=0;ni<4;ni++){ acc[mi][ni][0]=0.f; acc[mi][ni][1]=0.f; acc[mi][ni][2]=0.f; acc[mi][ni][3]=0.f; }

    for (int ks = 0; ks < 16; ks++){
        const int k0 = ks * 32;
        if (isA){
            if (Apk){       // layer 1: packed bf16 pairs
                const unsigned* src = Apk + (size_t)(row0 + sr) * HH + k0;
                u32x4 v[8];
                #pragma unroll
                for (int q=0;q<8;q++) v[q] = *(const u32x4*)(src + q*4);
                #pragma unroll
                for (int g=0; g<4; g++){
                    u32x4 h4, l4;
                    h4[0]=__builtin_amdgcn_perm(v[2*g][1],   v[2*g][0],   PERM_HI);
                    h4[1]=__builtin_amdgcn_perm(v[2*g][3],   v[2*g][2],   PERM_HI);
                    h4[2]=__builtin_amdgcn_perm(v[2*g+1][1], v[2*g+1][0], PERM_HI);
                    h4[3]=__builtin_amdgcn_perm(v[2*g+1][3], v[2*g+1][2], PERM_HI);
                    l4[0]=__builtin_amdgcn_perm(v[2*g][1],   v[2*g][0],   PERM_LO);
                    l4[1]=__builtin_amdgcn_perm(v[2*g][3],   v[2*g][2],   PERM_LO);
                    l4[2]=__builtin_amdgcn_perm(v[2*g+1][1], v[2*g+1][0], PERM_LO);
                    l4[3]=__builtin_amdgcn_perm(v[2*g+1][3], v[2*g+1][2], PERM_LO);
                    *(u32x4*)&Ah[sr][g*8] = h4;
                    *(u32x4*)&Al[sr][g*8] = l4;
                }
            } else {        // layer 0: fp32 gather + split
                const float* src = Af32 + (size_t)gather[row0 + sr] * HH + k0;
                float f[32];
                #pragma unroll
                for (int q=0;q<8;q++) *(float4*)&f[q*4] = *(const float4*)(src + q*4);
                #pragma unroll
                for (int g=0; g<4; g++){
                    unsigned short h[8], l[8];
                    #pragma unroll
                    for (int j=0;j<8;j++) split2(f[g*8+j], h[j], l[j]);
                    u32x4 h4, l4;
                    #pragma unroll
                    for (int q=0;q<4;q++){
                        h4[q] = (((unsigned)h[2*q+1])<<16) | (unsigned)h[2*q];
                        l4[q] = (((unsigned)l[2*q+1])<<16) | (unsigned)l[2*q];
                    }
                    *(u32x4*)&Ah[sr][g*8] = h4;
                    *(u32x4*)&Al[sr][g*8] = l4;
                }
            }
        } else {            // B rows (pre-split)
            const unsigned short* sh = Bhi + (size_t)(col0 + sr) * HH + k0;
            const unsigned short* sl = Blo + (size_t)(col0 + sr) * HH + k0;
            #pragma unroll
            for (int g=0; g<4; g++){
                *(u32x4*)&Bh[sr][g*8] = *(const u32x4*)(sh + g*8);
                *(u32x4*)&Bl[sr][g*8] = *(const u32x4*)(sl + g*8);
            }
        }
        __syncthreads();

        bf16x8 ah[4], al[4];
        #pragma unroll
        for (int mi=0;mi<4;mi++){
            ah[mi] = *(const bf16x8*)&Ah[wm + mi*16 + c16][kg*8];
            al[mi] = *(const bf16x8*)&Al[wm + mi*16 + c16][kg*8];
        }
        #pragma unroll
        for (int ni=0;ni<4;ni++){
            bf16x8 bh = *(const bf16x8*)&Bh[wn + ni*16 + c16][kg*8];
            bf16x8 bl = *(const bf16x8*)&Bl[wn + ni*16 + c16][kg*8];
            #pragma unroll
            for (int mi=0;mi<4;mi++){
                acc[mi][ni] = __builtin_amdgcn_mfma_f32_16x16x32_bf16(ah[mi], bh, acc[mi][ni], 0,0,0);
                acc[mi][ni] = __builtin_amdgcn_mfma_f32_16x16x32_bf16(ah[mi], bl, acc[mi][ni], 0,0,0);
                acc[mi][ni] = __builtin_amdgcn_mfma_f32_16x16x32_bf16(al[mi], bh, acc[mi][ni], 0,0,0);
            }
        }
        __syncthreads();
    }
    // epilogue
    float bs[4];
    #pragma unroll
    for (int ni=0;ni<4;ni++){
        int c = col0 + wn + ni*16 + c16;
        bs[ni] = bias1[c] + bias2[c];
    }
    #pragma unroll
    for (int mi=0;mi<4;mi++){
        #pragma unroll
        for (int i=0;i<4;i++){
            int R = row0 + wm + mi*16 + kg*4 + i;
            int b = R >> 8, t = R & 255;
            float* op = out + (size_t)(t*BB + b)*GG + col0 + wn;
            #pragma unroll
            for (int ni=0;ni<4;ni++)
                op[ni*16 + c16] = acc[mi][ni][i] + bs[ni];
        }
    }
}

// ---------------- persistent LSTM scan (split-bf16 MFMA, epoch barrier) ----------
// r12 + h REGISTER PREFETCH: all 16 u32x8 h fragments loaded at step top (fully
// unrolled -> ~128 VGPRs, 32 outstanding IF loads) to restore the memory-level
// parallelism lost when LDS-weights dropped VGPR pressure to 52 (r12 regression).
__global__ __launch_bounds__(256,1) void lstm_scan_mfma(
    const float* __restrict__ xg,            // [TT][BB][GG]
    const unsigned short* __restrict__ Whi,  // [GG][HH] bf16-hi
    const unsigned short* __restrict__ Wlo,  // [GG][HH] bf16-lo
    unsigned* __restrict__ hpk,              // [2][BB][HH] packed (lo<<16)|hi
    unsigned* __restrict__ hseq_pk,          // mode1: [BB*TT][HH] packed
    float* __restrict__ hlast,               // mode0: [BB][HH] fp32
    int* __restrict__ bar,                   // zeroed: [0]=epoch, 32+g*32 groups, 288 root
    int mode)
{
    __shared__ unsigned short Wh[8192];      // [kt][kg][16 rows][8]  (16 KB)
    __shared__ unsigned short Wl[8192];
    __shared__ float gs[BB][17];
    const int tid  = threadIdx.x;
    const int lane = tid & 63, wv = tid >> 6;
    const int wg   = blockIdx.x;
    const int j0   = wg * 4;
    const int c16  = lane & 15, kg = lane >> 4;

    // stage weight slice to LDS: thread = (row rr, k-tile kseg)
    {
        const int rr = tid >> 4, kseg = tid & 15;
        const int grow = (rr >> 2) * HH + j0 + (rr & 3);
        const unsigned short* ph = Whi + (size_t)grow * HH + kseg * 32;
        const unsigned short* pl = Wlo + (size_t)grow * HH + kseg * 32;
        #pragma unroll
        for (int g=0; g<4; g++){
            *(u32x4*)&Wh[((kseg*4 + g)*16 + rr)*8] = *(const u32x4*)(ph + g*8);
            *(u32x4*)&Wl[((kseg*4 + g)*16 + rr)*8] = *(const u32x4*)(pl + g*8);
        }
    }
    __syncthreads();

    const int arow = wv * 16 + c16;                    // A row (batch) this lane loads
    const int xcol = (c16 >> 2) * HH + j0 + (c16 & 3); // xg gate column
    const int b0   = wv * 16 + kg * 4;                 // D rows base (4 batches)
    const int ab   = tid >> 2, ad = tid & 3;           // activation: (batch, dim)

    float c_st = 0.f;

    // prime xg accumulator for t=0
    f32x4 cur;
    {
        const float* xp = xg + xcol;
        cur[0] = xp[(size_t)(b0 + 0) * GG];
        cur[1] = xp[(size_t)(b0 + 1) * GG];
        cur[2] = xp[(size_t)(b0 + 2) * GG];
        cur[3] = xp[(size_t)(b0 + 3) * GG];
    }

    for (int t = 0; t < TT; t++){
        const unsigned* hin  = hpk + (size_t)(t & 1) * BB * HH;
        unsigned*       hout = hpk + (size_t)((t + 1) & 1) * BB * HH;

        // ---- prefetch ALL h fragments into registers (deep IF pipeline) ----
        u32x8 hr[16];
        {
            const unsigned* pa = hin + (size_t)arow * HH + kg * 8;
            #pragma unroll
            for (int kt = 0; kt < 16; kt++)
                hr[kt] = *(const u32x8*)(pa + kt * 32);
        }

        f32x4 acc0 = cur;
        f32x4 acc1; acc1[0]=0.f; acc1[1]=0.f; acc1[2]=0.f; acc1[3]=0.f;
        #pragma unroll
        for (int kt = 0; kt < 16; kt++){
            u32x8 w = hr[kt];
            unsigned h01 = __builtin_amdgcn_perm(w[1], w[0], PERM_HI);
            unsigned h23 = __builtin_amdgcn_perm(w[3], w[2], PERM_HI);
            unsigned h45 = __builtin_amdgcn_perm(w[5], w[4], PERM_HI);
            unsigned h67 = __builtin_amdgcn_perm(w[7], w[6], PERM_HI);
            unsigned l01 = __builtin_amdgcn_perm(w[1], w[0], PERM_LO);
            unsigned l23 = __builtin_amdgcn_perm(w[3], w[2], PERM_LO);
            unsigned l45 = __builtin_amdgcn_perm(w[5], w[4], PERM_LO);
            unsigned l67 = __builtin_amdgcn_perm(w[7], w[6], PERM_LO);
            bf16x8 a_h = mk8(h01, h23, h45, h67);
            bf16x8 a_l = mk8(l01, l23, l45, l67);
            bf16x8 wbh = *(const bf16x8*)&Wh[((kt*4 + kg)*16 + c16)*8];
            bf16x8 wbl = *(const bf16x8*)&Wl[((kt*4 + kg)*16 + c16)*8];
            if (kt & 1){
                acc1 = __builtin_amdgcn_mfma_f32_16x16x32_bf16(a_h, wbh, acc1, 0,0,0);
                acc1 = __builtin_amdgcn_mfma_f32_16x16x32_bf16(a_h, wbl, acc1, 0,0,0);
                acc1 = __builtin_amdgcn_mfma_f32_16x16x32_bf16(a_l, wbh, acc1, 0,0,0);
            } else {
                acc0 = __builtin_amdgcn_mfma_f32_16x16x32_bf16(a_h, wbh, acc0, 0,0,0);
                acc0 = __builtin_amdgcn_mfma_f32_16x16x32_bf16(a_h, wbl, acc0, 0,0,0);
                acc0 = __builtin_amdgcn_mfma_f32_16x16x32_bf16(a_l, wbh, acc0, 0,0,0);
            }
        }
        // D -> LDS (lane holds D[b0+r][c16])
        gs[b0 + 0][c16] = acc0[0] + acc1[0];
        gs[b0 + 1][c16] = acc0[1] + acc1[1];
        gs[b0 + 2][c16] = acc0[2] + acc1[2];
        gs[b0 + 3][c16] = acc0[3] + acc1[3];
        __syncthreads();
        {
            float gi = gs[ab][ad], gf = gs[ab][4 + ad], gg = gs[ab][8 + ad], go = gs[ab][12 + ad];
            gi = 1.f / (1.f + expf(-gi));
            gf = 1.f / (1.f + expf(-gf));
            gg = tanhf(gg);
            go = 1.f / (1.f + expf(-go));
            c_st = gf * c_st + gi * gg;
            float h = go * tanhf(c_st);
            unsigned short hb, lb; split2(h, hb, lb);
            unsigned pk = (((unsigned)lb) << 16) | (unsigned)hb;
            __hip_atomic_store(&hout[(size_t)ab * HH + j0 + ad], pk,
                               __ATOMIC_RELAXED, __HIP_MEMORY_SCOPE_AGENT);
            if (mode) hseq_pk[(size_t)(ab * TT + t) * HH + j0 + ad] = pk;
            else      hlast[(size_t)ab * HH + j0 + ad] = h;
        }
        // ---- epoch barrier (round-9-validated) ----
        __syncthreads();
        if (tid == 0){
            const int g = wg & 7;
            int old = __hip_atomic_fetch_add(bar + 32 + g * 32, 1,
                        __ATOMIC_RELAXED, __HIP_MEMORY_SCOPE_AGENT);
            if (old == (NWG / 8) * (t + 1) - 1){
                int r = __hip_atomic_fetch_add(bar + 288, 1,
                            __ATOMIC_RELAXED, __HIP_MEMORY_SCOPE_AGENT);
                if (r == 8 * (t + 1) - 1){
                    __hip_atomic_store(bar, t + 1,
                        __ATOMIC_RELAXED, __HIP_MEMORY_SCOPE_AGENT);
                }
            }
        }
        // prefetch next-step xg into regs (overlaps the spin below)
        {
            const int tp = (t + 1 < TT) ? t + 1 : t;
            const float* xp = xg + (size_t)tp * BB * GG + xcol;
            cur[0] = xp[(size_t)(b0 + 0) * GG];
            cur[1] = xp[(size_t)(b0 + 1) * GG];
            cur[2] = xp[(size_t)(b0 + 2) * GG];
            cur[3] = xp[(size_t)(b0 + 3) * GG];
        }
        if (tid == 0){
            while (__hip_atomic_load(bar, __ATOMIC_RELAXED, __HIP_MEMORY_SCOPE_AGENT) < t + 1)
                __builtin_amdgcn_s_sleep(2);
            __builtin_amdgcn_fence(__ATOMIC_ACQUIRE, "agent");   // inv stale h lines
        }
        __syncthreads();
    }
}

// logits: out[b][v] = sum_k h[b][k]*W[v][k] + bias[v]; M=64, N=50257, K=512
__global__ __launch_bounds__(256) void gemm_logits(
    const float* __restrict__ hlast, const float* __restrict__ W,
    const float* __restrict__ bias, float* __restrict__ out)
{
    __shared__ float As[32][68];
    __shared__ float Bs[32][68];
    const int tid = threadIdx.x;
    const int col0 = blockIdx.x * 64;
    const int tx = tid & 15, ty = tid >> 4;
    float acc[4][4];
    #pragma unroll
    for (int i=0;i<4;i++)
        #pragma unroll
        for (int j=0;j<4;j++) acc[i][j]=0.f;

    for (int k0=0;k0<HH;k0+=32){
        #pragma unroll
        for (int i=0;i<2;i++){
            int f = tid + i*256;
            int r = f>>3, kq = f&7;
            float4 v = *(const float4*)(hlast + (size_t)r*HH + k0 + kq*4);
            As[kq*4+0][r]=v.x; As[kq*4+1][r]=v.y; As[kq*4+2][r]=v.z; As[kq*4+3][r]=v.w;
        }
        #pragma unroll
        for (int i=0;i<2;i++){
            int f = tid + i*256;
            int r = f>>3, kq = f&7;
            int vrow = col0 + r;
            float4 v = make_float4(0.f,0.f,0.f,0.f);
            if (vrow < NCLS) v = *(const float4*)(W + (size_t)vrow*HH + k0 + kq*4);
            Bs[kq*4+0][r]=v.x; Bs[kq*4+1][r]=v.y; Bs[kq*4+2][r]=v.z; Bs[kq*4+3][r]=v.w;
        }
        __syncthreads();
        #pragma unroll
        for (int kk=0;kk<32;kk++){
            float4 a4 = *(float4*)&As[kk][ty*4];
            float4 b4 = *(float4*)&Bs[kk][tx*4];
            float a[4] = {a4.x,a4.y,a4.z,a4.w};
            float b[4] = {b4.x,b4.y,b4.z,b4.w};
            #pragma unroll
            for (int i=0;i<4;i++)
                #pragma unroll
                for (int j=0;j<4;j++) acc[i][j] += a[i]*b[j];
        }
        __syncthreads();
    }
    #pragma unroll
    for (int i=0;i<4;i++){
        int b = ty*4 + i;
        #pragma unroll
        for (int j=0;j<4;j++){
            int v = col0 + tx*4 + j;
            if (v < NCLS) out[(size_t)b*NCLS + v] = acc[i][j] + bias[v];
        }
    }
}

extern "C" void kernel_launch(void* const* d_in, const int* in_sizes, int n_in,
                              void* d_out, int out_size, void* d_ws, size_t ws_size,
                              hipStream_t stream)
{
    const int*   X     = (const int*)  d_in[0];
    const float* emb   = (const float*)d_in[1];
    const float* w_ih0 = (const float*)d_in[2];
    const float* w_hh0 = (const float*)d_in[3];
    const float* b_ih0 = (const float*)d_in[4];
    const float* b_hh0 = (const float*)d_in[5];
    const float* w_ih1 = (const float*)d_in[6];
    const float* w_hh1 = (const float*)d_in[7];
    const float* b_ih1 = (const float*)d_in[8];
    const float* b_hh1 = (const float*)d_in[9];
    const float* Wout  = (const float*)d_in[10];
    const float* bout  = (const float*)d_in[11];
    float* out = (float*)d_out;

    float* ws = (float*)d_ws;
    float*          xg      = ws;                               // 33,554,432 f
    unsigned*       hseq_pk = (unsigned*)(ws + 33554432);       // 8,388,608 u32
    float*          hlast   = ws + 41943040;                    // 32,768 f
    unsigned short* Shi     = (unsigned short*)(ws + 41975808); // 1,048,576 shorts
    unsigned short* Slo     = (unsigned short*)(ws + 42500096);
    unsigned*       hpk     = (unsigned*)(ws + 43024384);       // 65,536 u32
    int*            bar     = (int*)(ws + 43089920);            // 4 KB
    // total 43,090,944 f = 172.4 MB

    dim3 gemmGrid(16, 128);

    // ---- layer 0
    split_bf16_k<<<4096, 256, 0, stream>>>(w_ih0, Shi, Slo, GG*HH);
    gemm_xg_mfma<<<gemmGrid, 256, 0, stream>>>(emb, nullptr, X, Shi, Slo, b_ih0, b_hh0, xg);
    split_bf16_k<<<4096, 256, 0, stream>>>(w_hh0, Shi, Slo, GG*HH);
    hipMemsetAsync(hpk, 0, (size_t)2*BB*HH*sizeof(unsigned), stream);
    hipMemsetAsync(bar, 0, 4096, stream);
    {
        const float* a0 = xg; const unsigned short *a1 = Shi, *a2 = Slo;
        unsigned* a3 = hpk; unsigned* a4 = hseq_pk; float* a5 = hlast; int* a6 = bar; int a7 = 1;
        void* args[] = {&a0,&a1,&a2,&a3,&a4,&a5,&a6,&a7};
        hipLaunchCooperativeKernel((void*)lstm_scan_mfma, dim3(NWG), dim3(256), args, 0, stream);
    }
    // ---- layer 1
    split_bf16_k<<<4096, 256, 0, stream>>>(w_ih1, Shi, Slo, GG*HH);
    gemm_xg_mfma<<<gemmGrid, 256, 0, stream>>>(nullptr, hseq_pk, nullptr, Shi, Slo, b_ih1, b_hh1, xg);
    split_bf16_k<<<4096, 256, 0, stream>>>(w_hh1, Shi, Slo, GG*HH);
    hipMemsetAsync(hpk, 0, (size_t)2*BB*HH*sizeof(unsigned), stream);
    hipMemsetAsync(bar, 0, 4096, stream);
    {
        const float* a0 = xg; const unsigned short *a1 = Shi, *a2 = Slo;
        unsigned* a3 = hpk; unsigned* a4 = hseq_pk; float* a5 = hlast; int* a6 = bar; int a7 = 0;
        void* args[] = {&a0,&a1,&a2,&a3,&a4,&a5,&a6,&a7};
        hipLaunchCooperativeKernel((void*)lstm_scan_mfma, dim3(NWG), dim3(256), args, 0, stream);
    }
    gemm_logits<<<786, 256, 0, stream>>>(hlast, Wout, bout, out);
}